// Round 4
// baseline (205.970 us; speedup 1.0000x reference)
//
#include <hip/hip_runtime.h>
#include <hip/hip_bf16.h>
#include <math.h>

#define D_DIM   4096
#define B_ROWS  4096
#define K_CODES 256
#define MARGIN  3.0      // |approx d2 - exact d2| <= ~1.5 worst-case; 3.0 window
#define KS      4        // K-split
#define KSLICE  (D_DIM / KS)   // 1024
#define BK      32

// output layout (f32 elements)
#define IDX_OFF   (B_ROWS * D_DIM)                 // 16777216
#define PROBS_OFF (IDX_OFF + B_ROWS)               // 16781312
#define LOSS_OFF  (PROBS_OFF + B_ROWS * K_CODES)   // 17829888

typedef __bf16 bf16x8 __attribute__((ext_vector_type(8)));
typedef float  f32x16 __attribute__((ext_vector_type(16)));

// ws: part[KS][4096][256] f32 (16 MB) | cbh[256][4096] u16 (2 MB) | cc[256] f64
//     | xxp[KS][4096] f32
#define PART_ELEMS ((size_t)KS * B_ROWS * K_CODES)

static __device__ inline unsigned short f2bf(float f) {
    __hip_bfloat16 h = __float2bfloat16(f);
    return *reinterpret_cast<unsigned short*>(&h);
}

// ---------------------------------------------------------------------------
// prep_cb: wave-per-codebook-row (256 rows): cbh bf16 + cc f64. 64 blocks.
// ---------------------------------------------------------------------------
__global__ __launch_bounds__(256) void prep_cb(const float* __restrict__ cb,
                                               unsigned short* __restrict__ cbh,
                                               double* __restrict__ cc) {
    const int lane = threadIdx.x & 63;
    const int k = blockIdx.x * 4 + (threadIdx.x >> 6);   // 0..255
    const float4* row4 = (const float4*)(cb + (size_t)k * D_DIM);
    ushort4* dst4 = (ushort4*)(cbh + (size_t)k * D_DIM);
    double a0 = 0.0, a1 = 0.0, a2 = 0.0, a3 = 0.0;
#pragma unroll
    for (int i = 0; i < 16; ++i) {
        float4 v = row4[i * 64 + lane];
        a0 += (double)v.x * v.x; a1 += (double)v.y * v.y;
        a2 += (double)v.z * v.z; a3 += (double)v.w * v.w;
        ushort4 h;
        h.x = f2bf(v.x); h.y = f2bf(v.y); h.z = f2bf(v.z); h.w = f2bf(v.w);
        dst4[i * 64 + lane] = h;
    }
    double s = (a0 + a1) + (a2 + a3);
    for (int off = 32; off; off >>= 1) s += __shfl_xor(s, off);
    if (lane == 0) cc[k] = s;
}

// ---------------------------------------------------------------------------
// gemm: block = 32 rows x 256 codes x KSLICE, grid (128, KS) = 512 blocks.
// B: bf16 via global_load_lds into double-buffered LDS, layout [q][code][8]
//    -> frag reads are lane-contiguous 16B (conflict-free).
// A: per-wave direct global f32 loads (round-2-verified frag addressing),
//    register double-buffered; converted to bf16 inline.
// One barrier per iter; manual vmcnt(4) drains current B-DMA while next-iter
// A loads stay in flight. Wave 0 also accumulates per-row sum(x^2) (f32).
// ---------------------------------------------------------------------------
__global__ __launch_bounds__(256, 2) void gemm(const float* __restrict__ x,
                                               const unsigned short* __restrict__ cbh,
                                               float* __restrict__ part,
                                               float* __restrict__ xxp) {
    __shared__ unsigned short Bs[2][K_CODES * BK];   // 2 x 16 KB
    const int t = threadIdx.x;
    const int lane = t & 63, w = t >> 6;
    const int h = lane >> 5, mr = lane & 31;
    const int m0 = blockIdx.x * 32;
    const int ks = blockIdx.y;
    const int k0 = ks * KSLICE;

    const unsigned short* bgp = cbh + (size_t)t * D_DIM + k0;       // code = t
    const float* xp = x + (size_t)(m0 + mr) * D_DIM + k0 + h * 8;

    // prologue: DMA B(iter0) -> buf 0; A(iter0) -> regs
#pragma unroll
    for (int r = 0; r < 4; ++r)
        __builtin_amdgcn_global_load_lds(
            (const __attribute__((address_space(1))) void*)(bgp + 8 * r),
            (__attribute__((address_space(3))) void*)(&Bs[0][(t + 256 * r) * 8]),
            16, 0, 0);
    float4 a0 = *(const float4*)(xp);
    float4 a1 = *(const float4*)(xp + 4);
    float4 a2 = *(const float4*)(xp + 16);
    float4 a3 = *(const float4*)(xp + 20);

    f32x16 acc0, acc1;
#pragma unroll
    for (int i = 0; i < 16; ++i) { acc0[i] = 0.f; acc1[i] = 0.f; }
    float sq = 0.f;

    int p = 0;
    for (int kk = 0; kk < KSLICE; kk += BK) {
        const int kn = (kk + BK < KSLICE) ? kk + BK : 0;   // clamped (valid addr)
        float4 n0 = *(const float4*)(xp + kn);
        float4 n1 = *(const float4*)(xp + kn + 4);
        float4 n2 = *(const float4*)(xp + kn + 16);
        float4 n3 = *(const float4*)(xp + kn + 20);

        bf16x8 af0, af1;
        af0[0] = (__bf16)a0.x; af0[1] = (__bf16)a0.y; af0[2] = (__bf16)a0.z; af0[3] = (__bf16)a0.w;
        af0[4] = (__bf16)a1.x; af0[5] = (__bf16)a1.y; af0[6] = (__bf16)a1.z; af0[7] = (__bf16)a1.w;
        af1[0] = (__bf16)a2.x; af1[1] = (__bf16)a2.y; af1[2] = (__bf16)a2.z; af1[3] = (__bf16)a2.w;
        af1[4] = (__bf16)a3.x; af1[5] = (__bf16)a3.y; af1[6] = (__bf16)a3.z; af1[7] = (__bf16)a3.w;
        if (w == 0) {   // wave-uniform branch: xx partials (f32, tolerance-safe)
            sq += a0.x*a0.x + a0.y*a0.y + a0.z*a0.z + a0.w*a0.w
                + a1.x*a1.x + a1.y*a1.y + a1.z*a1.z + a1.w*a1.w
                + a2.x*a2.x + a2.y*a2.y + a2.z*a2.z + a2.w*a2.w
                + a3.x*a3.x + a3.y*a3.y + a3.z*a3.z + a3.w*a3.w;
        }

        __builtin_amdgcn_s_waitcnt(0x0F74);  // vmcnt(4): drain buf-p DMA, keep n*
        __syncthreads();                     // all waves' DMA for buf p complete

        // DMA next iter's B into buf 1-p (overlaps compute below)
#pragma unroll
        for (int r = 0; r < 4; ++r)
            __builtin_amdgcn_global_load_lds(
                (const __attribute__((address_space(1))) void*)(bgp + kn + 8 * r),
                (__attribute__((address_space(3))) void*)(&Bs[1 - p][(t + 256 * r) * 8]),
                16, 0, 0);

#pragma unroll
        for (int s = 0; s < 2; ++s) {
            const int q = 2 * s + h;
            bf16x8 b0 = *(const bf16x8*)&Bs[p][(q * 256 + w * 64 + mr) * 8];
            bf16x8 b1 = *(const bf16x8*)&Bs[p][(q * 256 + w * 64 + 32 + mr) * 8];
            acc0 = __builtin_amdgcn_mfma_f32_32x32x16_bf16(s ? af1 : af0, b0, acc0, 0, 0, 0);
            acc1 = __builtin_amdgcn_mfma_f32_32x32x16_bf16(s ? af1 : af0, b1, acc1, 0, 0, 0);
        }
        a0 = n0; a1 = n1; a2 = n2; a3 = n3;
        p ^= 1;
    }

    if (w == 0) {
        float tot = sq + __shfl_xor(sq, 32);   // combine the two k-halves of row mr
        if (lane < 32) xxp[(size_t)ks * B_ROWS + m0 + mr] = tot;
    }
    float* dst = part + ((size_t)ks * B_ROWS + m0) * K_CODES + w * 64;
#pragma unroll
    for (int r = 0; r < 16; ++r) {
        const int rowit = (r & 3) + 8 * (r >> 2) + 4 * h;
        dst[(size_t)rowit * K_CODES + mr]      = acc0[r];
        dst[(size_t)rowit * K_CODES + 32 + mr] = acc1[r];
    }
}

// ---------------------------------------------------------------------------
// finish: wave-per-row. d2 from partials (f64), butterfly max, margin
// candidates; single candidate -> done; else exact f64 refinement (rare).
// Writes idx, loss, probs(=0), quant row. No LDS, no barriers.
// ---------------------------------------------------------------------------
__global__ __launch_bounds__(256) void finish(const float* __restrict__ x,
                                              const float* __restrict__ cb,
                                              const float* __restrict__ part,
                                              const double* __restrict__ cc,
                                              const float* __restrict__ xxp,
                                              float* __restrict__ out) {
    const int lane = threadIdx.x & 63;
    const int row = blockIdx.x * 4 + (threadIdx.x >> 6);

    double xx = ((double)xxp[row] + (double)xxp[B_ROWS + row])
              + ((double)xxp[2 * B_ROWS + row] + (double)xxp[3 * B_ROWS + row]);
    float4 p[KS];
#pragma unroll
    for (int s = 0; s < KS; ++s)
        p[s] = ((const float4*)(part + ((size_t)s * B_ROWS + row) * K_CODES))[lane];
    double v[4];
    v[0] = xx + cc[4 * lane + 0] - 2.0 * (((double)p[0].x + p[1].x) + ((double)p[2].x + p[3].x));
    v[1] = xx + cc[4 * lane + 1] - 2.0 * (((double)p[0].y + p[1].y) + ((double)p[2].y + p[3].y));
    v[2] = xx + cc[4 * lane + 2] - 2.0 * (((double)p[0].z + p[1].z) + ((double)p[2].z + p[3].z));
    v[3] = xx + cc[4 * lane + 3] - 2.0 * (((double)p[0].w + p[1].w) + ((double)p[2].w + p[3].w));

    double mx = fmax(fmax(v[0], v[1]), fmax(v[2], v[3]));
    for (int off = 32; off; off >>= 1) mx = fmax(mx, __shfl_xor(mx, off));
    const double thr = mx - MARGIN;

    unsigned long long b[4];
#pragma unroll
    for (int j = 0; j < 4; ++j) b[j] = __ballot(v[j] >= thr);
    const int total = __popcll(b[0]) + __popcll(b[1]) + __popcll(b[2]) + __popcll(b[3]);

    int bestk = 0; double best;
    if (total == 1) {
        best = mx;   // the lone candidate IS the max; error bound guarantees argmax
#pragma unroll
        for (int j = 0; j < 4; ++j)
            if (b[j]) bestk = 4 * (int)__builtin_ctzll(b[j]) + j;
    } else {
        const float4* xrow4 = (const float4*)(x + (size_t)row * D_DIM);
        int flags = 0;
#pragma unroll
        for (int j = 0; j < 4; ++j) if (v[j] >= thr) flags |= 1 << j;
        unsigned long long cand = __ballot(flags != 0);
        best = -1.0e300;
        while (cand) {
            const int lsrc = __builtin_ctzll(cand);
            cand &= cand - 1;
            const int f = __shfl(flags, lsrc);
            for (int j = 0; j < 4; ++j) {
                if (!((f >> j) & 1)) continue;
                const int k = 4 * lsrc + j;
                const float4* crow4 = (const float4*)(cb + (size_t)k * D_DIM);
                double a0 = 0.0, a1 = 0.0, a2 = 0.0, a3 = 0.0;
#pragma unroll
                for (int i = 0; i < 16; ++i) {
                    float4 xa = xrow4[i * 64 + lane];
                    float4 ca = crow4[i * 64 + lane];
                    a0 += (double)xa.x * ca.x; a1 += (double)xa.y * ca.y;
                    a2 += (double)xa.z * ca.z; a3 += (double)xa.w * ca.w;
                }
                double s = (a0 + a1) + (a2 + a3);
                for (int off = 32; off; off >>= 1) s += __shfl_xor(s, off);
                // exact d2 relative to refined dot; xx/cc shifts identical across k
                const double d2e = xx + cc[k] - 2.0 * s;
                if (d2e > best) { best = d2e; bestk = k; }  // ascending k, strict >
            }
        }
    }

    if (lane == 0) {
        out[IDX_OFF + row]  = (float)bestk;
        out[LOSS_OFF + row] = (float)(1.25 * best / (double)D_DIM);
    }
    // probs row = 0 (true value underflows f32)
    float4 z = make_float4(0.f, 0.f, 0.f, 0.f);
    ((float4*)(out + PROBS_OFF + (size_t)row * K_CODES))[lane] = z;
    // quant = codebook[bestk] (bestk uniform across wave)
    const float4* src = (const float4*)(cb + (size_t)bestk * D_DIM);
    float4* dst = (float4*)(out + (size_t)row * D_DIM);
#pragma unroll
    for (int i = 0; i < 16; ++i) dst[i * 64 + lane] = src[i * 64 + lane];
}

// ---------------------------------------------------------------------------
extern "C" void kernel_launch(void* const* d_in, const int* in_sizes, int n_in,
                              void* d_out, int out_size, void* d_ws, size_t ws_size,
                              hipStream_t stream) {
    const float* x  = (const float*)d_in[0];
    const float* cb = (const float*)d_in[1];
    float* out = (float*)d_out;

    float*          part = (float*)d_ws;
    unsigned short* cbh  = (unsigned short*)((char*)d_ws + PART_ELEMS * sizeof(float));
    double*         cc   = (double*)((char*)cbh + (size_t)K_CODES * D_DIM * sizeof(unsigned short));
    float*          xxp  = (float*)(cc + K_CODES);

    hipLaunchKernelGGL(prep_cb, dim3(64),       dim3(256), 0, stream, cb, cbh, cc);
    hipLaunchKernelGGL(gemm,    dim3(128, KS),  dim3(256), 0, stream, x, cbh, part, xxp);
    hipLaunchKernelGGL(finish,  dim3(1024),     dim3(256), 0, stream, x, cb, part, cc, xxp, out);
}

// Round 5
// 156.522 us; speedup vs baseline: 1.3159x; 1.3159x over previous
//
#include <hip/hip_runtime.h>
#include <hip/hip_bf16.h>
#include <math.h>

#define D_DIM   4096
#define B_ROWS  4096
#define K_CODES 256
#define MARGIN  3.0      // |approx d2 - exact d2| <= ~1.5 worst-case; 3.0 window
#define KS      4        // K-split
#define KSLICE  (D_DIM / KS)   // 1024
#define BK      64             // 16 iters per block
#define NITER   (KSLICE / BK)

// output layout (f32 elements)
#define IDX_OFF   (B_ROWS * D_DIM)                 // 16777216
#define PROBS_OFF (IDX_OFF + B_ROWS)               // 16781312
#define LOSS_OFF  (PROBS_OFF + B_ROWS * K_CODES)   // 17829888

typedef __bf16 bf16x8 __attribute__((ext_vector_type(8)));
typedef float  f32x16 __attribute__((ext_vector_type(16)));

// ws: part[KS][4096][256] f32 (16 MB) | cbh_sw (2 MB) | cc[256] f64 | xxp[KS][4096] f32
// cbh_sw layout: [panel = k/64][q = (k/8)&7][code][off = k&7] ushort
#define PART_ELEMS ((size_t)KS * B_ROWS * K_CODES)

static __device__ inline unsigned short f2bf(float f) {
    __hip_bfloat16 h = __float2bfloat16(f);
    return *reinterpret_cast<unsigned short*>(&h);
}

// ---------------------------------------------------------------------------
// prep_cb: wave-per-codebook-row. Writes swizzled bf16 codebook + cc (f64).
// ---------------------------------------------------------------------------
__global__ __launch_bounds__(256) void prep_cb(const float* __restrict__ cb,
                                               unsigned short* __restrict__ cbsw,
                                               double* __restrict__ cc) {
    const int lane = threadIdx.x & 63;
    const int k = blockIdx.x * 4 + (threadIdx.x >> 6);   // code 0..255
    const float4* row4 = (const float4*)(cb + (size_t)k * D_DIM);
    double a0 = 0.0, a1 = 0.0, a2 = 0.0, a3 = 0.0;
#pragma unroll
    for (int i = 0; i < 16; ++i) {
        float4 v = row4[i * 64 + lane];
        a0 += (double)v.x * v.x; a1 += (double)v.y * v.y;
        a2 += (double)v.z * v.z; a3 += (double)v.w * v.w;
        ushort4 h;
        h.x = f2bf(v.x); h.y = f2bf(v.y); h.z = f2bf(v.z); h.w = f2bf(v.w);
        const int c = (i * 64 + lane) * 4;           // global k of this chunk
        const int panel = c >> 6, q = (c >> 3) & 7, off = c & 7;
        *(ushort4*)&cbsw[(((size_t)panel * 8 + q) * K_CODES + k) * 8 + off] = h;
    }
    double s = (a0 + a1) + (a2 + a3);
    for (int off = 32; off; off >>= 1) s += __shfl_xor(s, off);
    if (lane == 0) cc[k] = s;
}

// ---------------------------------------------------------------------------
// gemm: block = 32 rows x 256 codes x KSLICE, grid (128, KS), 4 blocks/CU.
// B: swizzled bf16 codebook DMA'd linearly (fully coalesced) -> LDS layout
//    [q][code][8] -> frag reads lane-contiguous (conflict-free).
// A: coalesced f32 loads (128B per 8 lanes) -> bf16 -> LDS in frag order
//    [q][row][8] -> frag reads lane-contiguous. xx partials fused (f32).
// ---------------------------------------------------------------------------
__global__ __launch_bounds__(256, 4) void gemm(const float* __restrict__ x,
                                               const unsigned short* __restrict__ cbsw,
                                               float* __restrict__ part,
                                               float* __restrict__ xxp) {
    __shared__ unsigned short As[8 * 32 * 8];        // [q][row][8]  4 KB
    __shared__ unsigned short Bs[8 * K_CODES * 8];   // [q][code][8] 32 KB
    const int t = threadIdx.x;
    const int lane = t & 63, w = t >> 6;
    const int h = lane >> 5, mr = lane & 31;
    const int m0 = blockIdx.x * 32;
    const int ks = blockIdx.y;
    const int k0 = ks * KSLICE;

    // A staging: thread t -> row t>>3, cols 4*(t&7) and 4*(t&7)+32 of each BK tile
    const int arow = t >> 3, acg = 4 * (t & 7);
    const float* ag = x + (size_t)(m0 + arow) * D_DIM + k0 + acg;
    unsigned short* aw0 = &As[(((acg >> 3)    ) * 32 + arow) * 8 + (acg & 7)];
    unsigned short* aw1 = &As[(((acg >> 3) + 4) * 32 + arow) * 8 + (acg & 7)];
    // B DMA: linear in cbsw; per-iter stride = 64 k * 256 codes = 16384 ushort
    const unsigned short* bg = cbsw + (size_t)(ks * NITER) * 16384 + t * 8;

    f32x16 acc0, acc1;
#pragma unroll
    for (int i = 0; i < 16; ++i) { acc0[i] = 0.f; acc1[i] = 0.f; }
    float sq = 0.f;

    float4 a0 = *(const float4*)(ag);
    float4 a1 = *(const float4*)(ag + 32);
    for (int it = 0; it < NITER; ++it) {
        const int kn = (it + 1 < NITER) ? (it + 1) * BK : 0;   // clamped, valid
        float4 n0 = *(const float4*)(ag + kn);
        float4 n1 = *(const float4*)(ag + kn + 32);
        __syncthreads();   // previous iter's LDS frag reads complete
#pragma unroll
        for (int r = 0; r < 8; ++r)
            __builtin_amdgcn_global_load_lds(
                (const __attribute__((address_space(1))) void*)(bg + (size_t)it * 16384 + r * 2048),
                (__attribute__((address_space(3))) void*)(&Bs[(t + 256 * r) * 8]),
                16, 0, 0);
        ushort4 h0, h1;
        h0.x = f2bf(a0.x); h0.y = f2bf(a0.y); h0.z = f2bf(a0.z); h0.w = f2bf(a0.w);
        h1.x = f2bf(a1.x); h1.y = f2bf(a1.y); h1.z = f2bf(a1.z); h1.w = f2bf(a1.w);
        *(ushort4*)aw0 = h0;
        *(ushort4*)aw1 = h1;
        sq += a0.x*a0.x + a0.y*a0.y + a0.z*a0.z + a0.w*a0.w
            + a1.x*a1.x + a1.y*a1.y + a1.z*a1.z + a1.w*a1.w;
        __syncthreads();   // drains ds_write + DMA before frag reads
#pragma unroll
        for (int s = 0; s < 4; ++s) {
            const int q = 2 * s + h;
            bf16x8 af = *(const bf16x8*)&As[(q * 32 + mr) * 8];
            bf16x8 b0 = *(const bf16x8*)&Bs[(q * K_CODES + w * 64 + mr) * 8];
            bf16x8 b1 = *(const bf16x8*)&Bs[(q * K_CODES + w * 64 + 32 + mr) * 8];
            acc0 = __builtin_amdgcn_mfma_f32_32x32x16_bf16(af, b0, acc0, 0, 0, 0);
            acc1 = __builtin_amdgcn_mfma_f32_32x32x16_bf16(af, b1, acc1, 0, 0, 0);
        }
        a0 = n0; a1 = n1;
    }

    // xx partials: reduce sq over the 8 threads sharing a row (lanes t&7)
    sq += __shfl_xor(sq, 1);
    sq += __shfl_xor(sq, 2);
    sq += __shfl_xor(sq, 4);
    if ((t & 7) == 0) xxp[(size_t)ks * B_ROWS + m0 + arow] = sq;

    float* dst = part + ((size_t)ks * B_ROWS + m0) * K_CODES + w * 64;
#pragma unroll
    for (int r = 0; r < 16; ++r) {
        const int rowit = (r & 3) + 8 * (r >> 2) + 4 * h;
        dst[(size_t)rowit * K_CODES + mr]      = acc0[r];
        dst[(size_t)rowit * K_CODES + 32 + mr] = acc1[r];
    }
}

// ---------------------------------------------------------------------------
// finish: wave-per-row. d2 from partials (f64), butterfly max, margin
// candidates; single candidate -> done; else exact f64 refinement (rare).
// Writes idx, loss, probs(=0), quant row. No LDS, no barriers.
// ---------------------------------------------------------------------------
__global__ __launch_bounds__(256) void finish(const float* __restrict__ x,
                                              const float* __restrict__ cb,
                                              const float* __restrict__ part,
                                              const double* __restrict__ cc,
                                              const float* __restrict__ xxp,
                                              float* __restrict__ out) {
    const int lane = threadIdx.x & 63;
    const int row = blockIdx.x * 4 + (threadIdx.x >> 6);

    double xx = ((double)xxp[row] + (double)xxp[B_ROWS + row])
              + ((double)xxp[2 * B_ROWS + row] + (double)xxp[3 * B_ROWS + row]);
    float4 p[KS];
#pragma unroll
    for (int s = 0; s < KS; ++s)
        p[s] = ((const float4*)(part + ((size_t)s * B_ROWS + row) * K_CODES))[lane];
    double v[4];
    v[0] = xx + cc[4 * lane + 0] - 2.0 * (((double)p[0].x + p[1].x) + ((double)p[2].x + p[3].x));
    v[1] = xx + cc[4 * lane + 1] - 2.0 * (((double)p[0].y + p[1].y) + ((double)p[2].y + p[3].y));
    v[2] = xx + cc[4 * lane + 2] - 2.0 * (((double)p[0].z + p[1].z) + ((double)p[2].z + p[3].z));
    v[3] = xx + cc[4 * lane + 3] - 2.0 * (((double)p[0].w + p[1].w) + ((double)p[2].w + p[3].w));

    double mx = fmax(fmax(v[0], v[1]), fmax(v[2], v[3]));
    for (int off = 32; off; off >>= 1) mx = fmax(mx, __shfl_xor(mx, off));
    const double thr = mx - MARGIN;

    unsigned long long b[4];
#pragma unroll
    for (int j = 0; j < 4; ++j) b[j] = __ballot(v[j] >= thr);
    const int total = __popcll(b[0]) + __popcll(b[1]) + __popcll(b[2]) + __popcll(b[3]);

    int bestk = 0; double best;
    if (total == 1) {
        best = mx;   // lone candidate IS the max; error bound guarantees argmax
#pragma unroll
        for (int j = 0; j < 4; ++j)
            if (b[j]) bestk = 4 * (int)__builtin_ctzll(b[j]) + j;
    } else {
        const float4* xrow4 = (const float4*)(x + (size_t)row * D_DIM);
        int flags = 0;
#pragma unroll
        for (int j = 0; j < 4; ++j) if (v[j] >= thr) flags |= 1 << j;
        unsigned long long cand = __ballot(flags != 0);
        best = -1.0e300;
        while (cand) {
            const int lsrc = __builtin_ctzll(cand);
            cand &= cand - 1;
            const int f = __shfl(flags, lsrc);
            for (int j = 0; j < 4; ++j) {
                if (!((f >> j) & 1)) continue;
                const int k = 4 * lsrc + j;
                const float4* crow4 = (const float4*)(cb + (size_t)k * D_DIM);
                double a0 = 0.0, a1 = 0.0, a2 = 0.0, a3 = 0.0;
#pragma unroll
                for (int i = 0; i < 16; ++i) {
                    float4 xa = xrow4[i * 64 + lane];
                    float4 ca = crow4[i * 64 + lane];
                    a0 += (double)xa.x * ca.x; a1 += (double)xa.y * ca.y;
                    a2 += (double)xa.z * ca.z; a3 += (double)xa.w * ca.w;
                }
                double s = (a0 + a1) + (a2 + a3);
                for (int off = 32; off; off >>= 1) s += __shfl_xor(s, off);
                const double d2e = xx + cc[k] - 2.0 * s;    // identical across lanes
                if (d2e > best) { best = d2e; bestk = k; }  // ascending k, strict >
            }
        }
    }

    if (lane == 0) {
        out[IDX_OFF + row]  = (float)bestk;
        out[LOSS_OFF + row] = (float)(1.25 * best / (double)D_DIM);
    }
    float4 z = make_float4(0.f, 0.f, 0.f, 0.f);
    ((float4*)(out + PROBS_OFF + (size_t)row * K_CODES))[lane] = z;
    const float4* src = (const float4*)(cb + (size_t)bestk * D_DIM);
    float4* dst = (float4*)(out + (size_t)row * D_DIM);
#pragma unroll
    for (int i = 0; i < 16; ++i) dst[i * 64 + lane] = src[i * 64 + lane];
}

// ---------------------------------------------------------------------------
extern "C" void kernel_launch(void* const* d_in, const int* in_sizes, int n_in,
                              void* d_out, int out_size, void* d_ws, size_t ws_size,
                              hipStream_t stream) {
    const float* x  = (const float*)d_in[0];
    const float* cb = (const float*)d_in[1];
    float* out = (float*)d_out;

    float*          part = (float*)d_ws;
    unsigned short* cbsw = (unsigned short*)((char*)d_ws + PART_ELEMS * sizeof(float));
    double*         cc   = (double*)((char*)cbsw + (size_t)K_CODES * D_DIM * sizeof(unsigned short));
    float*          xxp  = (float*)(cc + K_CODES);

    hipLaunchKernelGGL(prep_cb, dim3(64),      dim3(256), 0, stream, cb, cbsw, cc);
    hipLaunchKernelGGL(gemm,    dim3(128, KS), dim3(256), 0, stream, x, cbsw, part, xxp);
    hipLaunchKernelGGL(finish,  dim3(1024),    dim3(256), 0, stream, x, cb, part, cc, xxp, out);
}